// Round 3
// 1212.534 us; speedup vs baseline: 1.0579x; 1.0579x over previous
//
#include <hip/hip_runtime.h>

// Problem constants
#define HH   1024
#define WW   2048
#define HWP  (HH * WW)          // 2,097,152 pixels
#define CC   34
#define NI   128
#define THING_LO 24
#define THING_HI 33
#define NTC  10                 // thing classes 24..33

// k1 chunking: each block owns a contiguous CHUNK of pixels so mask writes
// can be plane-major with long contiguous runs (32 KB/wave/plane).
#define CHUNK 8192              // pixels per block -> grid = HWP/CHUNK = 256
#define QPB   (CHUNK / 4)       // 2048 packed-u32 quads per block

typedef float nfloat4 __attribute__((ext_vector_type(4)));

// Output layout (all float32, concatenated in return order)
#define OFF_CLASS  ((size_t)NI * HWP)
#define OFF_PROBS  (OFF_CLASS + NI)
#define OFF_SEGP   (OFF_PROBS + NI)
#define OFF_TOTAL  (OFF_SEGP + NI)
#define OFF_VALID  (OFF_TOTAL + NI)

// Workspace layout (bytes)
#define WS_COUNTS  0                         // int[NI*NTC] = 5120 B
#define WS_CLS     (NI * NTC * 4)            // int[NI]
#define WS_INV     (WS_CLS + NI * 4)         // float[NI]

__device__ __forceinline__ int thing_inst(int s, int im) {
    return (s >= THING_LO && s <= THING_HI) ? im : 0;
}

// K1: two phases per 8192-pixel block.
//   Phase A: compute inst id per pixel (u8, 0..128), pack 4/word into LDS;
//            histogram (inst,class) pairs into an LDS 1280-bin histogram.
//   Flush:   per-block histogram -> global counts (fire-and-forget atomics).
//   Phase B: plane-major mask writes. Wave w owns planes [w*32, w*32+32);
//            per plane it streams the whole 32 KB chunk contiguously
//            (32 x 1 KB dwordx4 stores), reading inst bytes back from LDS.
//            Long runs restore HBM row locality (the old plane-interleaved
//            1 KB hops ran at ~1.7 TB/s vs 6.2 TB/s fill rate).
__global__ __launch_bounds__(256) void k1_mask_count(
    const int* __restrict__ seg, const int* __restrict__ imap,
    float* __restrict__ out_masks, int* __restrict__ counts)
{
    __shared__ uint32_t inst4[QPB];      // 8 KB packed inst bytes
    __shared__ int      hist[NI * NTC];  // 5 KB counts histogram

    const int tid = threadIdx.x;

    for (int i = tid; i < NI * NTC; i += 256) hist[i] = 0;
    __syncthreads();

    // ---- Phase A ----
    const int base_q = blockIdx.x * QPB;
    #pragma unroll
    for (int j = 0; j < QPB / 256; ++j) {           // 8 iterations
        const int q = base_q + j * 256 + tid;
        const int p = q * 4;
        const int4 sg = *reinterpret_cast<const int4*>(seg + p);
        const int4 im = *reinterpret_cast<const int4*>(imap + p);

        const int i0 = thing_inst(sg.x, im.x);
        const int i1 = thing_inst(sg.y, im.y);
        const int i2 = thing_inst(sg.z, im.z);
        const int i3 = thing_inst(sg.w, im.w);

        if (i0 > 0) atomicAdd(&hist[(i0 - 1) * NTC + (sg.x - THING_LO)], 1);
        if (i1 > 0) atomicAdd(&hist[(i1 - 1) * NTC + (sg.y - THING_LO)], 1);
        if (i2 > 0) atomicAdd(&hist[(i2 - 1) * NTC + (sg.z - THING_LO)], 1);
        if (i3 > 0) atomicAdd(&hist[(i3 - 1) * NTC + (sg.w - THING_LO)], 1);

        inst4[j * 256 + tid] = (uint32_t)i0 | ((uint32_t)i1 << 8) |
                               ((uint32_t)i2 << 16) | ((uint32_t)i3 << 24);
    }
    __syncthreads();

    // ---- Histogram flush (fire-and-forget; overlaps phase B) ----
    for (int i = tid; i < NI * NTC; i += 256) {
        const int v = hist[i];
        if (v) atomicAdd(&counts[i], v);
    }

    // ---- Phase B: plane-major mask stores ----
    const int w = tid >> 6;          // wave 0..3
    const int l = tid & 63;          // lane
    float* obase = out_masks + (size_t)blockIdx.x * CHUNK + (size_t)(l * 4);

    for (int ip = 0; ip < 32; ++ip) {
        const uint32_t id = (uint32_t)(w * 32 + ip + 1);   // instance 1..128
        float* o = obase + (size_t)(w * 32 + ip) * HWP;
        #pragma unroll 8
        for (int s = 0; s < 32; ++s) {
            const uint32_t qq = inst4[s * 64 + l];
            nfloat4 v;
            v.x = ((qq & 0xffu)         == id) ? 1.0f : 0.0f;
            v.y = (((qq >> 8)  & 0xffu) == id) ? 1.0f : 0.0f;
            v.z = (((qq >> 16) & 0xffu) == id) ? 1.0f : 0.0f;
            v.w = ((qq >> 24)           == id) ? 1.0f : 0.0f;
            *reinterpret_cast<nfloat4*>(o + s * 256) = v;  // 1 KB/wave, contiguous
        }
    }
}

// K2: one block of 128 threads. argmax over the 10 thing-class counts
// (strict > from low class == jnp.argmax first-max; all-zero row -> class 0).
__global__ __launch_bounds__(128) void k2_stats(
    const int* __restrict__ counts, const float* __restrict__ iprobs,
    float* __restrict__ out, int* __restrict__ cls_ws, float* __restrict__ inv_ws)
{
    const int i = threadIdx.x;      // 0..127 -> instance id i+1
    int bestv = 0, bestc = 0, tot = 0;
    #pragma unroll
    for (int j = 0; j < NTC; ++j) {
        const int c = counts[i * NTC + j];
        tot += c;
        if (c > bestv) { bestv = c; bestc = THING_LO + j; }
    }
    cls_ws[i] = bestc;
    inv_ws[i] = 1.0f / (float)(tot > 0 ? tot : 1);
    out[OFF_CLASS + i] = (float)bestc;
    out[OFF_PROBS + i] = iprobs[i];
    out[OFF_SEGP  + i] = 0.0f;
    out[OFF_TOTAL + i] = (float)tot;
    out[OFF_VALID + i] = (tot > 0) ? 1.0f : 0.0f;
}

// K3: gather probs[cls[inst]][pix] for things-pixels; LDS-accumulate per
// block; flush pre-divided partial into out[SEGP]. 1024 blocks
// (4 blocks/CU, 16 waves/CU) so the dependent gather->LDS-atomic chains
// have TLP to hide ~900cy HBM-miss latency (old 256-block grid = 1
// wave/SIMD, fully latency-exposed).
__global__ __launch_bounds__(256) void k3_segsum(
    const int* __restrict__ seg, const int* __restrict__ imap,
    const float* __restrict__ probs, const int* __restrict__ cls_ws,
    const float* __restrict__ inv_ws, float* __restrict__ out)
{
    __shared__ float lsum[NI];
    __shared__ int   scls[NI];
    if (threadIdx.x < NI) {
        lsum[threadIdx.x] = 0.0f;
        scls[threadIdx.x] = cls_ws[threadIdx.x];
    }
    __syncthreads();

    const int stride = gridDim.x * blockDim.x;
    for (int t = blockIdx.x * blockDim.x + threadIdx.x; t < HWP / 4; t += stride) {
        const int p = t * 4;
        const int4 sg = *reinterpret_cast<const int4*>(seg + p);
        const int4 im = *reinterpret_cast<const int4*>(imap + p);
        const int ii[4] = { thing_inst(sg.x, im.x), thing_inst(sg.y, im.y),
                            thing_inst(sg.z, im.z), thing_inst(sg.w, im.w) };
        #pragma unroll
        for (int k = 0; k < 4; ++k) {
            if (ii[k] > 0) {
                const int inst = ii[k] - 1;
                const size_t idx = (size_t)scls[inst] * HWP + (size_t)(p + k);
                atomicAdd(&lsum[inst], probs[idx]);
            }
        }
    }
    __syncthreads();
    if (threadIdx.x < NI) {
        const float v = lsum[threadIdx.x];
        if (v != 0.0f)
            atomicAdd(&out[OFF_SEGP + threadIdx.x], v * inv_ws[threadIdx.x]);
    }
}

extern "C" void kernel_launch(void* const* d_in, const int* in_sizes, int n_in,
                              void* d_out, int out_size, void* d_ws, size_t ws_size,
                              hipStream_t stream) {
    const int*   seg    = (const int*)d_in[0];     // (H,W) int32
    const int*   imap   = (const int*)d_in[1];     // (H,W) int32
    const float* probs  = (const float*)d_in[2];   // (C,H,W) f32
    const float* iprobs = (const float*)d_in[3];   // (NI,) f32
    float* out = (float*)d_out;

    char* ws = (char*)d_ws;
    int*   counts = (int*)(ws + WS_COUNTS);
    int*   cls_ws = (int*)(ws + WS_CLS);
    float* inv_ws = (float*)(ws + WS_INV);

    (void)hipMemsetAsync(counts, 0, NI * NTC * sizeof(int), stream);

    k1_mask_count<<<HWP / CHUNK, 256, 0, stream>>>(seg, imap, out, counts);
    k2_stats<<<1, 128, 0, stream>>>(counts, iprobs, out, cls_ws, inv_ws);
    k3_segsum<<<1024, 256, 0, stream>>>(seg, imap, probs, cls_ws, inv_ws, out);
}

// Round 4
// 1211.055 us; speedup vs baseline: 1.0592x; 1.0012x over previous
//
#include <hip/hip_runtime.h>

// Problem constants
#define HH   1024
#define WW   2048
#define HWP  (HH * WW)          // 2,097,152 pixels
#define CC   34
#define NI   128
#define THING_LO 24
#define THING_HI 33
#define NTC  10                 // thing classes 24..33

#define NW   (HWP / 4)          // 524,288 packed words (4 inst-bytes each)

// k1a: inst-byte compute, 256 blocks x 256 thr x 8 words
#define K1A_BLOCKS 256
#define K1A_WPT    8

// k1b: mask streamer, grid = 128 planes x 16 chunks = 2048 blocks (8/CU)
#define NCHUNK  16
#define CWORDS  (NW / NCHUNK)    // 32,768 words per chunk
#define CPIX    (HWP / NCHUNK)   // 131,072 pixels per chunk (512 KB contiguous)

typedef float nfloat4 __attribute__((ext_vector_type(4)));

// Output layout (all float32, concatenated in return order)
#define OFF_CLASS  ((size_t)NI * HWP)
#define OFF_PROBS  (OFF_CLASS + NI)
#define OFF_SEGP   (OFF_PROBS + NI)
#define OFF_TOTAL  (OFF_SEGP + NI)
#define OFF_VALID  (OFF_TOTAL + NI)

// Workspace layout (bytes)
#define WS_COUNTS  0                         // int[NI*NTC] = 5120 B
#define WS_CLS     (NI * NTC * 4)            // int[NI]
#define WS_INV     (WS_CLS + NI * 4)         // float[NI]
#define WS_INST    8192                      // u32[NW] = 2 MB packed inst bytes

__device__ __forceinline__ int thing_inst(int s, int im) {
    return (s >= THING_LO && s <= THING_HI) ? im : 0;
}

// K1a: compute per-pixel instance id (u8, 0..128), pack 4/word into the 2 MB
// workspace; LDS-histogram (inst,class) counts, flush once per block.
// Small kernel (~17 MB read, 2 MB write) — not the bottleneck.
__global__ __launch_bounds__(256) void k1a_inst(
    const int* __restrict__ seg, const int* __restrict__ imap,
    uint32_t* __restrict__ instw, int* __restrict__ counts)
{
    __shared__ int hist[NI * NTC];   // 5 KB
    const int tid = threadIdx.x;
    for (int i = tid; i < NI * NTC; i += 256) hist[i] = 0;
    __syncthreads();

    const int base = blockIdx.x * (K1A_WPT * 256);
    #pragma unroll
    for (int j = 0; j < K1A_WPT; ++j) {
        const int q = base + j * 256 + tid;
        const int p = q * 4;
        const int4 sg = *reinterpret_cast<const int4*>(seg + p);
        const int4 im = *reinterpret_cast<const int4*>(imap + p);

        const int i0 = thing_inst(sg.x, im.x);
        const int i1 = thing_inst(sg.y, im.y);
        const int i2 = thing_inst(sg.z, im.z);
        const int i3 = thing_inst(sg.w, im.w);

        if (i0 > 0) atomicAdd(&hist[(i0 - 1) * NTC + (sg.x - THING_LO)], 1);
        if (i1 > 0) atomicAdd(&hist[(i1 - 1) * NTC + (sg.y - THING_LO)], 1);
        if (i2 > 0) atomicAdd(&hist[(i2 - 1) * NTC + (sg.z - THING_LO)], 1);
        if (i3 > 0) atomicAdd(&hist[(i3 - 1) * NTC + (sg.w - THING_LO)], 1);

        instw[q] = (uint32_t)i0 | ((uint32_t)i1 << 8) |
                   ((uint32_t)i2 << 16) | ((uint32_t)i3 << 24);
    }
    __syncthreads();

    for (int i = tid; i < NI * NTC; i += 256) {
        const int v = hist[i];
        if (v) atomicAdd(&counts[i], v);
    }
}

// K1b: pure mask streamer at full occupancy. Block = (plane, chunk).
// Writes 512 KB fully contiguous per block (1 KB per wave store, shaped like
// the 6.26 TB/s harness fill: 2048 long streams, 8 blocks/CU, 32 waves/CU).
// Reads inst words coalesced (256 B/wave) from the L2-resident 2 MB ws —
// each chunk's 128 KB is shared by the 128 concurrently-running plane-blocks.
__global__ __launch_bounds__(256) void k1b_masks(
    const uint32_t* __restrict__ instw, float* __restrict__ out_masks)
{
    const int plane = blockIdx.x & (NI - 1);     // 0..127
    const int chunk = blockIdx.x >> 7;           // 0..15
    const uint32_t id = (uint32_t)(plane + 1);   // instance id 1..128

    const uint32_t* src = instw + (size_t)chunk * CWORDS;
    float* dst = out_masks + (size_t)plane * HWP + (size_t)chunk * CPIX;
    const int tid = threadIdx.x;

    #pragma unroll 4
    for (int i = 0; i < CWORDS / 256; ++i) {     // 128 iterations
        const uint32_t qq = src[i * 256 + tid];
        nfloat4 v;
        v.x = ((qq & 0xffu)         == id) ? 1.0f : 0.0f;
        v.y = (((qq >> 8)  & 0xffu) == id) ? 1.0f : 0.0f;
        v.z = (((qq >> 16) & 0xffu) == id) ? 1.0f : 0.0f;
        v.w = ((qq >> 24)           == id) ? 1.0f : 0.0f;
        *reinterpret_cast<nfloat4*>(dst + (size_t)(i * 256 + tid) * 4) = v;
    }
}

// K2: one block of 128 threads. argmax over the 10 thing-class counts
// (strict > from low class == jnp.argmax first-max; all-zero row -> class 0).
__global__ __launch_bounds__(128) void k2_stats(
    const int* __restrict__ counts, const float* __restrict__ iprobs,
    float* __restrict__ out, int* __restrict__ cls_ws, float* __restrict__ inv_ws)
{
    const int i = threadIdx.x;      // 0..127 -> instance id i+1
    int bestv = 0, bestc = 0, tot = 0;
    #pragma unroll
    for (int j = 0; j < NTC; ++j) {
        const int c = counts[i * NTC + j];
        tot += c;
        if (c > bestv) { bestv = c; bestc = THING_LO + j; }
    }
    cls_ws[i] = bestc;
    inv_ws[i] = 1.0f / (float)(tot > 0 ? tot : 1);
    out[OFF_CLASS + i] = (float)bestc;
    out[OFF_PROBS + i] = iprobs[i];
    out[OFF_SEGP  + i] = 0.0f;
    out[OFF_TOTAL + i] = (float)tot;
    out[OFF_VALID + i] = (tot > 0) ? 1.0f : 0.0f;
}

// K3: gather probs[cls[inst]][pix] for thing-pixels, driven by the 2 MB
// inst-word array (L2-warm from k1a/k1b; replaces the 16.8 MB seg+imap
// re-read). LDS-accumulate per block; flush pre-divided partial into
// out[SEGP]. 1024 blocks = 4 blocks/CU, 16 waves/CU for gather latency TLP.
__global__ __launch_bounds__(256) void k3_segsum(
    const uint32_t* __restrict__ instw, const float* __restrict__ probs,
    const int* __restrict__ cls_ws, const float* __restrict__ inv_ws,
    float* __restrict__ out)
{
    __shared__ float lsum[NI];
    __shared__ int   scls[NI];
    if (threadIdx.x < NI) {
        lsum[threadIdx.x] = 0.0f;
        scls[threadIdx.x] = cls_ws[threadIdx.x];
    }
    __syncthreads();

    const int stride = gridDim.x * blockDim.x;
    for (int q = blockIdx.x * blockDim.x + threadIdx.x; q < NW; q += stride) {
        const uint32_t wv = instw[q];
        if (wv) {
            const int p = q * 4;
            #pragma unroll
            for (int k = 0; k < 4; ++k) {
                const int inst = (int)((wv >> (8 * k)) & 0xffu);
                if (inst) {
                    const size_t idx = (size_t)scls[inst - 1] * HWP + (size_t)(p + k);
                    atomicAdd(&lsum[inst - 1], probs[idx]);
                }
            }
        }
    }
    __syncthreads();
    if (threadIdx.x < NI) {
        const float v = lsum[threadIdx.x];
        if (v != 0.0f)
            atomicAdd(&out[OFF_SEGP + threadIdx.x], v * inv_ws[threadIdx.x]);
    }
}

extern "C" void kernel_launch(void* const* d_in, const int* in_sizes, int n_in,
                              void* d_out, int out_size, void* d_ws, size_t ws_size,
                              hipStream_t stream) {
    const int*   seg    = (const int*)d_in[0];     // (H,W) int32
    const int*   imap   = (const int*)d_in[1];     // (H,W) int32
    const float* probs  = (const float*)d_in[2];   // (C,H,W) f32
    const float* iprobs = (const float*)d_in[3];   // (NI,) f32
    float* out = (float*)d_out;

    char* ws = (char*)d_ws;
    int*      counts = (int*)(ws + WS_COUNTS);
    int*      cls_ws = (int*)(ws + WS_CLS);
    float*    inv_ws = (float*)(ws + WS_INV);
    uint32_t* instw  = (uint32_t*)(ws + WS_INST);

    (void)hipMemsetAsync(counts, 0, NI * NTC * sizeof(int), stream);

    k1a_inst <<<K1A_BLOCKS, 256, 0, stream>>>(seg, imap, instw, counts);
    k2_stats <<<1, 128, 0, stream>>>(counts, iprobs, out, cls_ws, inv_ws);
    k1b_masks<<<NI * NCHUNK, 256, 0, stream>>>(instw, out);
    k3_segsum<<<1024, 256, 0, stream>>>(instw, probs, cls_ws, inv_ws, out);
}